// Round 6
// baseline (71.018 us; speedup 1.0000x reference)
//
#include <hip/hip_runtime.h>
#include <stdint.h>

typedef __bf16 bf16x8 __attribute__((ext_vector_type(8)));
typedef float  f32x4  __attribute__((ext_vector_type(4)));

typedef __attribute__((address_space(1))) const void g_void;
typedef __attribute__((address_space(3))) void l_void;

constexpr int NB = 32, TT = 2048, JJ = 512, DD = 256;
constexpr int CTX_ROWS = NB * TT;                 // 65536
constexpr int QUE_ROWS = NB * JJ;                 // 16384

// d_ws layout (bytes):
//   ctxb  [0,        33554432)   bf16[32][2048][256]
//   queb  [33554432, 41943040)   bf16[32][512][256]
//   cterm [41943040, 42205184)   f32[32][2048]
//   qterm [42205184, 42270720)   f32[32][512]
constexpr size_t WS_QUEB  = 33554432;
constexpr size_t WS_CTERM = 41943040;
constexpr size_t WS_QTERM = 42205184;
constexpr size_t WS_NEED  = 42270720;

// ================= kernel 1: convert + term dots (memory-bound) =============
// blocks [0,2048) -> ctx (4 iters of 8 rows), [2048,2560) -> que (4 iters).
__global__ __launch_bounds__(256)
void prep_kernel(const float* __restrict__ ctx, const float* __restrict__ que,
                 const float* __restrict__ wvec,
                 __bf16* __restrict__ ctxb, __bf16* __restrict__ queb,
                 float* __restrict__ cterm, float* __restrict__ qterm)
{
    const int tid  = threadIdx.x;
    const int colg = tid & 31;        // 32 col-groups x 8 f32 = 256
    const int rloc = tid >> 5;        // 8 rows per block-iter
    const int k0   = colg * 8;

    const bool isC = (blockIdx.x < 2048);
    const float* src0  = isC ? ctx  : que;
    __bf16*      dst0  = isC ? ctxb : queb;
    float*       term0 = isC ? cterm : qterm;
    const int    rows   = isC ? CTX_ROWS : QUE_ROWS;
    const int    stride = isC ? 2048 * 8 : 512 * 8;
    const int    rg0    = isC ? blockIdx.x : blockIdx.x - 2048;

    const f32x4 wd0 = *(const f32x4*)(wvec + (isC ? 0 : DD) + k0);
    const f32x4 wd1 = *(const f32x4*)(wvec + (isC ? 0 : DD) + k0 + 4);
    f32x4 wm0 = {1.f, 1.f, 1.f, 1.f}, wm1 = {1.f, 1.f, 1.f, 1.f};
    if (isC) { wm0 = *(const f32x4*)(wvec + 2 * DD + k0);
               wm1 = *(const f32x4*)(wvec + 2 * DD + k0 + 4); }

    for (int r = rg0 * 8 + rloc; r < rows; r += stride) {
        const float* src = src0 + (size_t)r * DD + k0;
        const f32x4 x0 = *(const f32x4*)src;
        const f32x4 x1 = *(const f32x4*)(src + 4);

        float d = x0[0]*wd0[0] + x0[1]*wd0[1] + x0[2]*wd0[2] + x0[3]*wd0[3]
                + x1[0]*wd1[0] + x1[1]*wd1[1] + x1[2]*wd1[2] + x1[3]*wd1[3];
        d += __shfl_xor(d, 1);  d += __shfl_xor(d, 2);  d += __shfl_xor(d, 4);
        d += __shfl_xor(d, 8);  d += __shfl_xor(d, 16);

        bf16x8 pk;
        #pragma unroll
        for (int j = 0; j < 4; ++j) {
            pk[j]     = (__bf16)(x0[j] * wm0[j]);
            pk[4 + j] = (__bf16)(x1[j] * wm1[j]);
        }
        *(bf16x8*)(dst0 + (size_t)r * DD + k0) = pk;
        if (colg == 0) term0[r] = d;
    }
}

// ================= kernel 2: bf16 MFMA GEMM + term epilogue ==================
// LDS: sA bf16[128][64] @0 (16KB), sB @16384 (16KB). 16B chunk c of row r at
// slot c^(r&7); DMA writes linearly, source carries inverse permutation.
__global__ __launch_bounds__(256)
void gemm_kernel(const __bf16* __restrict__ ctxb, const __bf16* __restrict__ queb,
                 const float* __restrict__ cterm, const float* __restrict__ qterm,
                 float* __restrict__ out)
{
    __shared__ __align__(1024) unsigned char lds[32768];

    const int tid = threadIdx.x;
    const int l   = tid & 63;
    const int wid = tid >> 6;

    // XCD-aware swizzle: each XCD gets 256 consecutive work-ids (4 batches).
    const int pb = blockIdx.x;
    const int id = (pb & 7) * 256 + (pb >> 3);
    const int n0 = (id & 3) * 128;
    const int m0 = ((id >> 2) & 15) * 128;
    const int bI = id >> 6;

    // --- DMA staging: per wave 8 issues; issue j covers rows wid*32+j*8..+8
    const int lrow8 = l >> 3;                 // 0..7
    const int lslot = l & 7;
    const int srcsw = (lslot ^ lrow8) << 3;   // swizzled chunk (element offset)

    const __bf16* aBase = ctxb + ((size_t)bI * TT + m0 + wid * 32 + lrow8) * DD + srcsw;
    const __bf16* bBase = queb + ((size_t)bI * JJ + n0 + wid * 32 + lrow8) * DD + srcsw;
    unsigned char* ldsA = lds + wid * 4096;
    unsigned char* ldsB = lds + 16384 + wid * 4096;

    auto stage = [&](int k) {
        #pragma unroll
        for (int j = 0; j < 4; ++j) {
            __builtin_amdgcn_global_load_lds((g_void*)(aBase + (size_t)j * 8 * DD + k * 64),
                                             (l_void*)(ldsA + j * 1024), 16, 0, 0);
            __builtin_amdgcn_global_load_lds((g_void*)(bBase + (size_t)j * 8 * DD + k * 64),
                                             (l_void*)(ldsB + j * 1024), 16, 0, 0);
        }
    };

    stage(0);

    f32x4 acc[4][4];
    #pragma unroll
    for (int m = 0; m < 4; ++m)
        #pragma unroll
        for (int n = 0; n < 4; ++n) acc[m][n] = f32x4{0.f, 0.f, 0.f, 0.f};

    const int wm_0 = (wid >> 1) * 64;
    const int wn_0 = (wid & 1) * 64;
    const int lr = l & 15;
    const int hi = l >> 4;

    #pragma unroll
    for (int k = 0; k < 4; ++k) {
        asm volatile("s_waitcnt vmcnt(0)" ::: "memory");   // tile k DMA done
        __builtin_amdgcn_s_barrier();

        bf16x8 af[2][4], bfr[2][4];
        #pragma unroll
        for (int kk = 0; kk < 2; ++kk) {
            const int c = kk * 4 + hi;
            #pragma unroll
            for (int m = 0; m < 4; ++m) {
                const int r = wm_0 + m * 16 + lr;
                af[kk][m] = *(const bf16x8*)(lds + r * 128 + ((c ^ (r & 7)) << 4));
            }
            #pragma unroll
            for (int n = 0; n < 4; ++n) {
                const int r = wn_0 + n * 16 + lr;
                bfr[kk][n] = *(const bf16x8*)(lds + 16384 + r * 128 + ((c ^ (r & 7)) << 4));
            }
        }
        asm volatile("s_waitcnt lgkmcnt(0)" ::: "memory"); // frag reads retired
        __builtin_amdgcn_sched_barrier(0);
        __builtin_amdgcn_s_barrier();                      // safe to overwrite tile
        if (k < 3) stage(k + 1);                           // DMA flight ∥ MFMA below

        // swapped operands: lane holds 4 consecutive output COLUMNS
        __builtin_amdgcn_s_setprio(1);
        #pragma unroll
        for (int kk = 0; kk < 2; ++kk)
            #pragma unroll
            for (int m = 0; m < 4; ++m)
                #pragma unroll
                for (int n = 0; n < 4; ++n)
                    acc[m][n] = __builtin_amdgcn_mfma_f32_16x16x32_bf16(bfr[kk][n], af[kk][m],
                                                                        acc[m][n], 0, 0, 0);
        __builtin_amdgcn_s_setprio(0);
    }

    // --- epilogue: lane l, reg q -> out[t = wm_0+m*16+lr][j = wn_0+n*16+hi*4+q]
    const int jb = wn_0 + hi * 4;
    #pragma unroll
    for (int m = 0; m < 4; ++m) {
        const int rowL = wm_0 + m * 16 + lr;
        const float cv = cterm[(size_t)bI * TT + m0 + rowL];
        float* rowp = out + ((size_t)bI * TT + m0 + rowL) * JJ + n0;
        #pragma unroll
        for (int n = 0; n < 4; ++n) {
            const int colL = jb + n * 16;
            const f32x4 qv = *(const f32x4*)(qterm + (size_t)bI * JJ + n0 + colL);
            const f32x4 v = acc[m][n];
            f32x4 w = {v[0] + cv + qv[0], v[1] + cv + qv[1],
                       v[2] + cv + qv[2], v[3] + cv + qv[3]};
            __builtin_nontemporal_store(w, (f32x4*)(rowp + colL));
        }
    }
}

// ================= fallback (only if ws too small; correctness-only) ========
__global__ __launch_bounds__(256)
void naive_kernel(const float* __restrict__ ctx, const float* __restrict__ que,
                  const float* __restrict__ wvec, float* __restrict__ out)
{
    const int j = blockIdx.x * 16 + (threadIdx.x & 15);
    const int t = blockIdx.y * 16 + (threadIdx.x >> 4);
    const int b = blockIdx.z;
    const float* cr = ctx + ((size_t)b * TT + t) * DD;
    const float* qr = que + ((size_t)b * JJ + j) * DD;
    float s = 0.f, ct = 0.f, qt = 0.f;
    for (int k = 0; k < DD; ++k) {
        const float cv = cr[k], qv = qr[k];
        s  += cv * wvec[2 * DD + k] * qv;
        ct += cv * wvec[k];
        qt += qv * wvec[DD + k];
    }
    out[((size_t)b * TT + t) * JJ + j] = s + ct + qt;
}

extern "C" void kernel_launch(void* const* d_in, const int* in_sizes, int n_in,
                              void* d_out, int out_size, void* d_ws, size_t ws_size,
                              hipStream_t stream) {
    (void)in_sizes; (void)n_in; (void)out_size;
    const float* ctx = (const float*)d_in[0];
    const float* que = (const float*)d_in[1];
    const float* wv  = (const float*)d_in[2];
    float* out = (float*)d_out;

    if (ws_size < WS_NEED) {
        naive_kernel<<<dim3(JJ / 16, TT / 16, NB), dim3(256), 0, stream>>>(ctx, que, wv, out);
        return;
    }

    __bf16* ctxb = (__bf16*)d_ws;
    __bf16* queb = (__bf16*)((char*)d_ws + WS_QUEB);
    float*  cterm = (float*)((char*)d_ws + WS_CTERM);
    float*  qterm = (float*)((char*)d_ws + WS_QTERM);

    prep_kernel<<<dim3(2560), dim3(256), 0, stream>>>(ctx, que, wv, ctxb, queb, cterm, qterm);
    gemm_kernel<<<dim3(2048), dim3(256), 0, stream>>>(ctxb, queb, cterm, qterm, out);
}

// Round 7
// 62.014 us; speedup vs baseline: 1.1452x; 1.1452x over previous
//
#include <hip/hip_runtime.h>
#include <stdint.h>

typedef __bf16 bf16x8 __attribute__((ext_vector_type(8)));
typedef float  f32x4  __attribute__((ext_vector_type(4)));

typedef __attribute__((address_space(1))) const void g_void;
typedef __attribute__((address_space(3))) void l_void;

constexpr int NB = 32, TT = 2048, JJ = 512, DD = 256;
constexpr int CTX_ROWS = NB * TT;                 // 65536
constexpr int QUE_ROWS = NB * JJ;                 // 16384

// d_ws layout (bytes):
//   ctxb  [0,        33554432)   bf16[32][2048][256]
//   queb  [33554432, 41943040)   bf16[32][512][256]
//   cterm [41943040, 42205184)   f32[32][2048]
//   qterm [42205184, 42270720)   f32[32][512]
constexpr size_t WS_QUEB  = 33554432;
constexpr size_t WS_CTERM = 41943040;
constexpr size_t WS_QTERM = 42205184;
constexpr size_t WS_NEED  = 42270720;

// ================= kernel 1: convert + term dots (memory-bound) =============
// blocks [0,2048) -> ctx (4 iters of 8 rows), [2048,2560) -> que (4 iters).
__global__ __launch_bounds__(256)
void prep_kernel(const float* __restrict__ ctx, const float* __restrict__ que,
                 const float* __restrict__ wvec,
                 __bf16* __restrict__ ctxb, __bf16* __restrict__ queb,
                 float* __restrict__ cterm, float* __restrict__ qterm)
{
    const int tid  = threadIdx.x;
    const int colg = tid & 31;        // 32 col-groups x 8 f32 = 256
    const int rloc = tid >> 5;        // 8 rows per block-iter
    const int k0   = colg * 8;

    const bool isC = (blockIdx.x < 2048);
    const float* src0  = isC ? ctx  : que;
    __bf16*      dst0  = isC ? ctxb : queb;
    float*       term0 = isC ? cterm : qterm;
    const int    rows   = isC ? CTX_ROWS : QUE_ROWS;
    const int    stride = isC ? 2048 * 8 : 512 * 8;
    const int    rg0    = isC ? blockIdx.x : blockIdx.x - 2048;

    const f32x4 wd0 = *(const f32x4*)(wvec + (isC ? 0 : DD) + k0);
    const f32x4 wd1 = *(const f32x4*)(wvec + (isC ? 0 : DD) + k0 + 4);
    f32x4 wm0 = {1.f, 1.f, 1.f, 1.f}, wm1 = {1.f, 1.f, 1.f, 1.f};
    if (isC) { wm0 = *(const f32x4*)(wvec + 2 * DD + k0);
               wm1 = *(const f32x4*)(wvec + 2 * DD + k0 + 4); }

    for (int r = rg0 * 8 + rloc; r < rows; r += stride) {
        const float* src = src0 + (size_t)r * DD + k0;
        const f32x4 x0 = *(const f32x4*)src;
        const f32x4 x1 = *(const f32x4*)(src + 4);

        float d = x0[0]*wd0[0] + x0[1]*wd0[1] + x0[2]*wd0[2] + x0[3]*wd0[3]
                + x1[0]*wd1[0] + x1[1]*wd1[1] + x1[2]*wd1[2] + x1[3]*wd1[3];
        d += __shfl_xor(d, 1);  d += __shfl_xor(d, 2);  d += __shfl_xor(d, 4);
        d += __shfl_xor(d, 8);  d += __shfl_xor(d, 16);

        bf16x8 pk;
        #pragma unroll
        for (int j = 0; j < 4; ++j) {
            pk[j]     = (__bf16)(x0[j] * wm0[j]);
            pk[4 + j] = (__bf16)(x1[j] * wm1[j]);
        }
        *(bf16x8*)(dst0 + (size_t)r * DD + k0) = pk;
        if (colg == 0) term0[r] = d;
    }
}

// ================= kernel 2: bf16 MFMA GEMM + term epilogue ==================
// LDS: sA bf16[128][64] @0 (16KB), sB @16384 (16KB). 16B chunk c of row r at
// slot c^(r&7); DMA writes linearly, source carries inverse permutation.
__global__ __launch_bounds__(256)
void gemm_kernel(const __bf16* __restrict__ ctxb, const __bf16* __restrict__ queb,
                 const float* __restrict__ cterm, const float* __restrict__ qterm,
                 float* __restrict__ out)
{
    __shared__ __align__(1024) unsigned char lds[32768];

    const int tid = threadIdx.x;
    const int l   = tid & 63;
    const int wid = tid >> 6;

    // XCD-aware swizzle: each XCD gets 256 consecutive work-ids (4 batches).
    const int pb = blockIdx.x;
    const int id = (pb & 7) * 256 + (pb >> 3);
    const int n0 = (id & 3) * 128;
    const int m0 = ((id >> 2) & 15) * 128;
    const int bI = id >> 6;

    // --- DMA staging: per wave 8 issues; issue j covers rows wid*32+j*8..+8
    const int lrow8 = l >> 3;                 // 0..7
    const int lslot = l & 7;
    const int srcsw = (lslot ^ lrow8) << 3;   // swizzled chunk (element offset)

    const __bf16* aBase = ctxb + ((size_t)bI * TT + m0 + wid * 32 + lrow8) * DD + srcsw;
    const __bf16* bBase = queb + ((size_t)bI * JJ + n0 + wid * 32 + lrow8) * DD + srcsw;
    unsigned char* ldsA = lds + wid * 4096;
    unsigned char* ldsB = lds + 16384 + wid * 4096;

    auto stage = [&](int k) {
        #pragma unroll
        for (int j = 0; j < 4; ++j) {
            __builtin_amdgcn_global_load_lds((g_void*)(aBase + (size_t)j * 8 * DD + k * 64),
                                             (l_void*)(ldsA + j * 1024), 16, 0, 0);
            __builtin_amdgcn_global_load_lds((g_void*)(bBase + (size_t)j * 8 * DD + k * 64),
                                             (l_void*)(ldsB + j * 1024), 16, 0, 0);
        }
    };

    stage(0);

    f32x4 acc[4][4];
    #pragma unroll
    for (int m = 0; m < 4; ++m)
        #pragma unroll
        for (int n = 0; n < 4; ++n) acc[m][n] = f32x4{0.f, 0.f, 0.f, 0.f};

    const int wm_0 = (wid >> 1) * 64;
    const int wn_0 = (wid & 1) * 64;
    const int lr = l & 15;
    const int hi = l >> 4;

    #pragma unroll
    for (int k = 0; k < 4; ++k) {
        asm volatile("s_waitcnt vmcnt(0)" ::: "memory");   // tile k DMA done
        __builtin_amdgcn_s_barrier();

        bf16x8 af[2][4], bfr[2][4];
        #pragma unroll
        for (int kk = 0; kk < 2; ++kk) {
            const int c = kk * 4 + hi;
            #pragma unroll
            for (int m = 0; m < 4; ++m) {
                const int r = wm_0 + m * 16 + lr;
                af[kk][m] = *(const bf16x8*)(lds + r * 128 + ((c ^ (r & 7)) << 4));
            }
            #pragma unroll
            for (int n = 0; n < 4; ++n) {
                const int r = wn_0 + n * 16 + lr;
                bfr[kk][n] = *(const bf16x8*)(lds + 16384 + r * 128 + ((c ^ (r & 7)) << 4));
            }
        }
        asm volatile("s_waitcnt lgkmcnt(0)" ::: "memory"); // frag reads retired
        __builtin_amdgcn_sched_barrier(0);
        __builtin_amdgcn_s_barrier();                      // safe to overwrite tile
        if (k < 3) stage(k + 1);                           // DMA flight ∥ MFMA below

        // swapped operands: lane holds 4 consecutive output COLUMNS
        __builtin_amdgcn_s_setprio(1);
        #pragma unroll
        for (int kk = 0; kk < 2; ++kk)
            #pragma unroll
            for (int m = 0; m < 4; ++m)
                #pragma unroll
                for (int n = 0; n < 4; ++n)
                    acc[m][n] = __builtin_amdgcn_mfma_f32_16x16x32_bf16(bfr[kk][n], af[kk][m],
                                                                        acc[m][n], 0, 0, 0);
        __builtin_amdgcn_s_setprio(0);
    }

    // --- epilogue: lane l, reg q -> out[t = wm_0+m*16+lr][j = wn_0+n*16+hi*4+q]
    const int jb = wn_0 + hi * 4;
    #pragma unroll
    for (int m = 0; m < 4; ++m) {
        const int rowL = wm_0 + m * 16 + lr;
        const float cv = cterm[(size_t)bI * TT + m0 + rowL];
        float* rowp = out + ((size_t)bI * TT + m0 + rowL) * JJ + n0;
        #pragma unroll
        for (int n = 0; n < 4; ++n) {
            const int colL = jb + n * 16;
            const f32x4 qv = *(const f32x4*)(qterm + (size_t)bI * JJ + n0 + colL);
            const f32x4 v = acc[m][n];
            f32x4 w = {v[0] + cv + qv[0], v[1] + cv + qv[1],
                       v[2] + cv + qv[2], v[3] + cv + qv[3]};
            *(f32x4*)(rowp + colL) = w;      // plain store: L2 write-back merges lines
        }
    }
}

// ================= fallback (only if ws too small; correctness-only) ========
__global__ __launch_bounds__(256)
void naive_kernel(const float* __restrict__ ctx, const float* __restrict__ que,
                  const float* __restrict__ wvec, float* __restrict__ out)
{
    const int j = blockIdx.x * 16 + (threadIdx.x & 15);
    const int t = blockIdx.y * 16 + (threadIdx.x >> 4);
    const int b = blockIdx.z;
    const float* cr = ctx + ((size_t)b * TT + t) * DD;
    const float* qr = que + ((size_t)b * JJ + j) * DD;
    float s = 0.f, ct = 0.f, qt = 0.f;
    for (int k = 0; k < DD; ++k) {
        const float cv = cr[k], qv = qr[k];
        s  += cv * wvec[2 * DD + k] * qv;
        ct += cv * wvec[k];
        qt += qv * wvec[DD + k];
    }
    out[((size_t)b * TT + t) * JJ + j] = s + ct + qt;
}

extern "C" void kernel_launch(void* const* d_in, const int* in_sizes, int n_in,
                              void* d_out, int out_size, void* d_ws, size_t ws_size,
                              hipStream_t stream) {
    (void)in_sizes; (void)n_in; (void)out_size;
    const float* ctx = (const float*)d_in[0];
    const float* que = (const float*)d_in[1];
    const float* wv  = (const float*)d_in[2];
    float* out = (float*)d_out;

    if (ws_size < WS_NEED) {
        naive_kernel<<<dim3(JJ / 16, TT / 16, NB), dim3(256), 0, stream>>>(ctx, que, wv, out);
        return;
    }

    __bf16* ctxb = (__bf16*)d_ws;
    __bf16* queb = (__bf16*)((char*)d_ws + WS_QUEB);
    float*  cterm = (float*)((char*)d_ws + WS_CTERM);
    float*  qterm = (float*)((char*)d_ws + WS_QTERM);

    prep_kernel<<<dim3(2560), dim3(256), 0, stream>>>(ctx, que, wv, ctxb, queb, cterm, qterm);
    gemm_kernel<<<dim3(2048), dim3(256), 0, stream>>>(ctxb, queb, cterm, qterm, out);
}

// Round 8
// 61.243 us; speedup vs baseline: 1.1596x; 1.0126x over previous
//
#include <hip/hip_runtime.h>
#include <stdint.h>

typedef __bf16 bf16x8 __attribute__((ext_vector_type(8)));
typedef float  f32x4  __attribute__((ext_vector_type(4)));

typedef __attribute__((address_space(1))) const void g_void;
typedef __attribute__((address_space(3))) void l_void;

constexpr int NB = 32, TT = 2048, JJ = 512, DD = 256;
constexpr int CTX_ROWS = NB * TT;                 // 65536
constexpr int QUE_ROWS = NB * JJ;                 // 16384

// d_ws layout (bytes):
//   ctxb  [0,        33554432)   bf16[32][2048][256]
//   queb  [33554432, 41943040)   bf16[32][512][256]
//   cterm [41943040, 42205184)   f32[32][2048]
//   qterm [42205184, 42270720)   f32[32][512]
constexpr size_t WS_QUEB  = 33554432;
constexpr size_t WS_CTERM = 41943040;
constexpr size_t WS_QTERM = 42205184;
constexpr size_t WS_NEED  = 42270720;

// ================= kernel 1: convert + term dots (memory-bound) =============
// blocks [0,2048) -> ctx (4 iters of 8 rows), [2048,2560) -> que (4 iters).
__global__ __launch_bounds__(256)
void prep_kernel(const float* __restrict__ ctx, const float* __restrict__ que,
                 const float* __restrict__ wvec,
                 __bf16* __restrict__ ctxb, __bf16* __restrict__ queb,
                 float* __restrict__ cterm, float* __restrict__ qterm)
{
    const int tid  = threadIdx.x;
    const int colg = tid & 31;        // 32 col-groups x 8 f32 = 256
    const int rloc = tid >> 5;        // 8 rows per block-iter
    const int k0   = colg * 8;

    const bool isC = (blockIdx.x < 2048);
    const float* src0  = isC ? ctx  : que;
    __bf16*      dst0  = isC ? ctxb : queb;
    float*       term0 = isC ? cterm : qterm;
    const int    rows   = isC ? CTX_ROWS : QUE_ROWS;
    const int    stride = isC ? 2048 * 8 : 512 * 8;
    const int    rg0    = isC ? blockIdx.x : blockIdx.x - 2048;

    const f32x4 wd0 = *(const f32x4*)(wvec + (isC ? 0 : DD) + k0);
    const f32x4 wd1 = *(const f32x4*)(wvec + (isC ? 0 : DD) + k0 + 4);
    f32x4 wm0 = {1.f, 1.f, 1.f, 1.f}, wm1 = {1.f, 1.f, 1.f, 1.f};
    if (isC) { wm0 = *(const f32x4*)(wvec + 2 * DD + k0);
               wm1 = *(const f32x4*)(wvec + 2 * DD + k0 + 4); }

    for (int r = rg0 * 8 + rloc; r < rows; r += stride) {
        const float* src = src0 + (size_t)r * DD + k0;
        const f32x4 x0 = *(const f32x4*)src;
        const f32x4 x1 = *(const f32x4*)(src + 4);

        float d = x0[0]*wd0[0] + x0[1]*wd0[1] + x0[2]*wd0[2] + x0[3]*wd0[3]
                + x1[0]*wd1[0] + x1[1]*wd1[1] + x1[2]*wd1[2] + x1[3]*wd1[3];
        d += __shfl_xor(d, 1);  d += __shfl_xor(d, 2);  d += __shfl_xor(d, 4);
        d += __shfl_xor(d, 8);  d += __shfl_xor(d, 16);

        bf16x8 pk;
        #pragma unroll
        for (int j = 0; j < 4; ++j) {
            pk[j]     = (__bf16)(x0[j] * wm0[j]);
            pk[4 + j] = (__bf16)(x1[j] * wm1[j]);
        }
        *(bf16x8*)(dst0 + (size_t)r * DD + k0) = pk;
        if (colg == 0) term0[r] = d;
    }
}

// ================= kernel 2: bf16 MFMA GEMM, 2-deep DMA pipeline =============
// LDS 32 KB: A0[0,8K) A1[8K,16K) B0[16K,24K) B1[24K,32K).
// Tile 128x32 bf16 = 8 KB, rows 64 B = 4x16B slots; chunk c of row r stored at
// slot c ^ ((r>>1)&3). DMA writes linearly; source address carries the inverse
// permutation (m173 pattern). Counted vmcnt keeps next tile in flight.
__global__ __launch_bounds__(256)
void gemm_kernel(const __bf16* __restrict__ ctxb, const __bf16* __restrict__ queb,
                 const float* __restrict__ cterm, const float* __restrict__ qterm,
                 float* __restrict__ out)
{
    __shared__ __align__(1024) unsigned char lds[32768];

    const int tid = threadIdx.x;
    const int l   = tid & 63;
    const int wid = tid >> 6;

    // XCD-aware swizzle: each XCD gets 256 consecutive work-ids (4 batches).
    const int pb = blockIdx.x;
    const int id = (pb & 7) * 256 + (pb >> 3);
    const int n0 = (id & 3) * 128;
    const int m0 = ((id >> 2) & 15) * 128;
    const int bI = id >> 6;

    // --- DMA staging: thread t -> row t>>2 (+64 on issue 1), 16B slot t&3.
    const int srow  = wid * 16 + (l >> 2);                    // 0..63
    const int schunk = ((l & 3) ^ ((srow >> 1) & 3)) << 3;    // swizzled source chunk (elements)

    const __bf16* aBase = ctxb + ((size_t)bI * TT + m0 + srow) * DD + schunk;
    const __bf16* bBase = queb + ((size_t)bI * JJ + n0 + srow) * DD + schunk;
    unsigned char* ldsW = lds + wid * 1024;   // wave-uniform LDS base

    auto stage = [&](int k, int b) {          // 4 loads / thread
        #pragma unroll
        for (int j = 0; j < 2; ++j) {
            __builtin_amdgcn_global_load_lds((g_void*)(aBase + (size_t)j * 64 * DD + k * 32),
                                             (l_void*)(ldsW + b * 8192 + j * 4096), 16, 0, 0);
            __builtin_amdgcn_global_load_lds((g_void*)(bBase + (size_t)j * 64 * DD + k * 32),
                                             (l_void*)(ldsW + 16384 + b * 8192 + j * 4096), 16, 0, 0);
        }
    };

    stage(0, 0);
    stage(1, 1);          // 8 loads outstanding

    f32x4 acc[4][4];
    #pragma unroll
    for (int m = 0; m < 4; ++m)
        #pragma unroll
        for (int n = 0; n < 4; ++n) acc[m][n] = f32x4{0.f, 0.f, 0.f, 0.f};

    const int wm_0 = (wid >> 1) * 64;
    const int wn_0 = (wid & 1) * 64;
    const int lr = l & 15;
    const int hi = l >> 4;

    #pragma unroll
    for (int k = 0; k < 8; ++k) {
        // steady state: wait for tile k only; tile k+1 stays in flight
        if (k < 7) asm volatile("s_waitcnt vmcnt(4)" ::: "memory");
        else       asm volatile("s_waitcnt vmcnt(0)" ::: "memory");
        __builtin_amdgcn_s_barrier();

        const unsigned char* bA = lds + (k & 1) * 8192;
        const unsigned char* bB = bA + 16384;

        bf16x8 af[4], bfr[4];
        #pragma unroll
        for (int m = 0; m < 4; ++m) {
            const int r = wm_0 + m * 16 + lr;
            af[m] = *(const bf16x8*)(bA + r * 64 + ((hi ^ ((r >> 1) & 3)) << 4));
        }
        #pragma unroll
        for (int n = 0; n < 4; ++n) {
            const int r = wn_0 + n * 16 + lr;
            bfr[n] = *(const bf16x8*)(bB + r * 64 + ((hi ^ ((r >> 1) & 3)) << 4));
        }
        asm volatile("s_waitcnt lgkmcnt(0)" ::: "memory"); // frag reads retired
        __builtin_amdgcn_sched_barrier(0);
        __builtin_amdgcn_s_barrier();                      // all reads of buf k&1 done
        if (k < 6) stage(k + 2, k & 1);                    // refill just-freed buffer

        // swapped operands: lane holds 4 consecutive output COLUMNS
        __builtin_amdgcn_s_setprio(1);
        #pragma unroll
        for (int m = 0; m < 4; ++m)
            #pragma unroll
            for (int n = 0; n < 4; ++n)
                acc[m][n] = __builtin_amdgcn_mfma_f32_16x16x32_bf16(bfr[n], af[m],
                                                                    acc[m][n], 0, 0, 0);
        __builtin_amdgcn_s_setprio(0);
    }

    // --- epilogue: lane l, reg q -> out[t = wm_0+m*16+lr][j = wn_0+n*16+hi*4+q]
    const int jb = wn_0 + hi * 4;
    #pragma unroll
    for (int m = 0; m < 4; ++m) {
        const int rowL = wm_0 + m * 16 + lr;
        const float cv = cterm[(size_t)bI * TT + m0 + rowL];
        float* rowp = out + ((size_t)bI * TT + m0 + rowL) * JJ + n0;
        #pragma unroll
        for (int n = 0; n < 4; ++n) {
            const int colL = jb + n * 16;
            const f32x4 qv = *(const f32x4*)(qterm + (size_t)bI * JJ + n0 + colL);
            const f32x4 v = acc[m][n];
            f32x4 w = {v[0] + cv + qv[0], v[1] + cv + qv[1],
                       v[2] + cv + qv[2], v[3] + cv + qv[3]};
            *(f32x4*)(rowp + colL) = w;      // plain store: L2 write-back merges lines
        }
    }
}

// ================= fallback (only if ws too small; correctness-only) ========
__global__ __launch_bounds__(256)
void naive_kernel(const float* __restrict__ ctx, const float* __restrict__ que,
                  const float* __restrict__ wvec, float* __restrict__ out)
{
    const int j = blockIdx.x * 16 + (threadIdx.x & 15);
    const int t = blockIdx.y * 16 + (threadIdx.x >> 4);
    const int b = blockIdx.z;
    const float* cr = ctx + ((size_t)b * TT + t) * DD;
    const float* qr = que + ((size_t)b * JJ + j) * DD;
    float s = 0.f, ct = 0.f, qt = 0.f;
    for (int k = 0; k < DD; ++k) {
        const float cv = cr[k], qv = qr[k];
        s  += cv * wvec[2 * DD + k] * qv;
        ct += cv * wvec[k];
        qt += qv * wvec[DD + k];
    }
    out[((size_t)b * TT + t) * JJ + j] = s + ct + qt;
}

extern "C" void kernel_launch(void* const* d_in, const int* in_sizes, int n_in,
                              void* d_out, int out_size, void* d_ws, size_t ws_size,
                              hipStream_t stream) {
    (void)in_sizes; (void)n_in; (void)out_size;
    const float* ctx = (const float*)d_in[0];
    const float* que = (const float*)d_in[1];
    const float* wv  = (const float*)d_in[2];
    float* out = (float*)d_out;

    if (ws_size < WS_NEED) {
        naive_kernel<<<dim3(JJ / 16, TT / 16, NB), dim3(256), 0, stream>>>(ctx, que, wv, out);
        return;
    }

    __bf16* ctxb = (__bf16*)d_ws;
    __bf16* queb = (__bf16*)((char*)d_ws + WS_QUEB);
    float*  cterm = (float*)((char*)d_ws + WS_CTERM);
    float*  qterm = (float*)((char*)d_ws + WS_QTERM);

    prep_kernel<<<dim3(2560), dim3(256), 0, stream>>>(ctx, que, wv, ctxb, queb, cterm, qterm);
    gemm_kernel<<<dim3(2048), dim3(256), 0, stream>>>(ctxb, queb, cterm, qterm, out);
}